// Round 15
// baseline (514.787 us; speedup 1.0000x reference)
//
#include <hip/hip_runtime.h>
#include <math.h>

#define NN 32768       // nodes
#define NE 524288      // edges
#define NB 256         // graphs/batch
#define HID 64
#define NL 3
#define EPS_AGG 1e-6f
#define EPS_BN 1e-5f
#define AGG_BLOCKS 2048
#define EF_BLOCKS 2048
#define NG_BLOCKS 2048
#define NBANK 16
// stats layout: [0 .. NBANK*256) banked accumulators {esum,esq,hsum,hsq}x64
// [4096..4159] e-scale  [4160..4223] e-shift  [4224..4287] h-scale  [4288..4351] h-shift
#define S_ESC 4096
#define S_ESH 4160
#define S_HSC 4224
#define S_HSH 4288

typedef _Float16 h16;
typedef h16 h16x8 __attribute__((ext_vector_type(8)));
typedef h16 h16x4 __attribute__((ext_vector_type(4)));
typedef float f32x4 __attribute__((ext_vector_type(4)));

#define MFMA16(a, b, c) __builtin_amdgcn_mfma_f32_16x16x32_f16(a, b, c, 0, 0, 0)

// ---------------- utility ----------------

__global__ void k_zero4(float4* __restrict__ p, long n4) {
    long t = (long)blockIdx.x * blockDim.x + threadIdx.x;
    long stride = (long)gridDim.x * blockDim.x;
    float4 z = {0.f, 0.f, 0.f, 0.f};
    for (; t < n4; t += stride) p[t] = z;
}

// ---------------- CSR build (counting sort by dst) ----------------

__global__ void k_hist(const int* __restrict__ dst, int* __restrict__ hist) {
    int i = blockIdx.x * blockDim.x + threadIdx.x;   // NE threads
    atomicAdd(&hist[dst[i]], 1);
}

__global__ void k_scan(const int* __restrict__ hist, int* __restrict__ rowptr,
                       int* __restrict__ cursor) {
    __shared__ int part[1024];
    int t = threadIdx.x;
    int loc[32];
    int base = t * 32, sum = 0;
#pragma unroll
    for (int k = 0; k < 32; ++k) { loc[k] = hist[base + k]; sum += loc[k]; }
    part[t] = sum;
    __syncthreads();
    for (int off = 1; off < 1024; off <<= 1) {
        int v = (t >= off) ? part[t - off] : 0;
        __syncthreads();
        part[t] += v;
        __syncthreads();
    }
    int ex = part[t] - sum;
#pragma unroll
    for (int k = 0; k < 32; ++k) {
        rowptr[base + k] = ex; cursor[base + k] = ex; ex += loc[k];
    }
    if (t == 1023) rowptr[NN] = ex;
}

__global__ void k_scatter(const int* __restrict__ src, const int* __restrict__ dst,
                          int* __restrict__ cursor, int* __restrict__ eperm,
                          int* __restrict__ src_s, int* __restrict__ dst_s) {
    int i = blockIdx.x * blockDim.x + threadIdx.x;   // NE threads
    int d = dst[i];
    int pos = atomicAdd(&cursor[d], 1);
    eperm[pos] = i;
    src_s[pos] = src[i];
    dst_s[pos] = d;
}

// ---------------- graph rowptr (gid is sorted) ----------------

__global__ void k_ghist(const int* __restrict__ gid, int* __restrict__ ghist) {
    int i = blockIdx.x * blockDim.x + threadIdx.x;   // NN threads
    atomicAdd(&ghist[gid[i]], 1);
}

__global__ void k_gscan(const int* __restrict__ ghist, int* __restrict__ grp) {
    __shared__ int part[256];
    int t = threadIdx.x;   // 256
    int v = ghist[t];
    part[t] = v;
    __syncthreads();
    for (int off = 1; off < 256; off <<= 1) {
        int u = (t >= off) ? part[t - off] : 0;
        __syncthreads();
        part[t] += u;
        __syncthreads();
    }
    grp[t + 1] = part[t];
    if (t == 0) grp[0] = 0;
}

// ---------------- node embedding ----------------

__global__ void k_embed_h(const float* __restrict__ hin, const float* __restrict__ W,
                          const float* __restrict__ b, float* __restrict__ out,
                          h16* __restrict__ out16) {
    int tid = blockIdx.x * blockDim.x + threadIdx.x;   // NN*64 threads
    int i = tid >> 6, j = tid & 63;
    float acc = b[j];
#pragma unroll
    for (int k = 0; k < 6; ++k) acc += hin[i * 6 + k] * W[k * 64 + j];
    out[tid] = acc;
    out16[tid] = (h16)acc;
}

// ---------------- node GEMM (MFMA): one wave per (tile, matrix) -----------------

__global__ void k_node_gemm(const h16* __restrict__ X,
                            const float* __restrict__ AW, const float* __restrict__ Ab,
                            const float* __restrict__ BW, const float* __restrict__ Bb,
                            const float* __restrict__ DW, const float* __restrict__ Db,
                            const float* __restrict__ EW, const float* __restrict__ Eb,
                            float* __restrict__ Ah, h16* __restrict__ Bh,
                            h16* __restrict__ Dh, h16* __restrict__ Eh) {
    __shared__ float tr[4][16][68];
    int lane = threadIdx.x & 63, wid = threadIdx.x >> 6;
    int wg = blockIdx.x * 4 + wid;            // 0..8191
    int m = wg & 3, tile = wg >> 2;           // tile < NN/16
    int ar = lane & 15, ak = (lane >> 4) * 8;
    int r = lane >> 2, c0 = (lane & 3) * 16;
    const float* W  = (m == 0) ? AW : (m == 1) ? BW : (m == 2) ? DW : EW;
    const float* Bb_ = (m == 0) ? Ab : (m == 1) ? Bb : (m == 2) ? Db : Eb;
    h16x8 wb0[4], wb1[4];
    float bias[4];
#pragma unroll
    for (int ct = 0; ct < 4; ++ct) {
        int col = ct * 16 + ar;
#pragma unroll
        for (int k = 0; k < 8; ++k) {
            wb0[ct][k] = (h16)W[(ak + k) * 64 + col];
            wb1[ct][k] = (h16)W[(32 + ak + k) * 64 + col];
        }
        bias[ct] = Bb_[col];
    }
    int row0 = tile * 16;
    h16x8 a0 = *(const h16x8*)&X[(size_t)(row0 + ar) * 64 + ak];
    h16x8 a1 = *(const h16x8*)&X[(size_t)(row0 + ar) * 64 + 32 + ak];
#pragma unroll
    for (int ct = 0; ct < 4; ++ct) {
        float bv = bias[ct];
        f32x4 acc = (f32x4){bv, bv, bv, bv};
        acc = MFMA16(a0, wb0[ct], acc);
        acc = MFMA16(a1, wb1[ct], acc);
#pragma unroll
        for (int j = 0; j < 4; ++j)
            tr[wid][(lane >> 4) * 4 + j][ct * 16 + ar] = acc[j];
    }
    // tr[wid] wave-private: no barrier
    if (m == 0) {
#pragma unroll
        for (int j = 0; j < 4; ++j)
            *(float4*)&Ah[(size_t)(row0 + r) * 64 + c0 + j * 4] =
                *(float4*)&tr[wid][r][c0 + j * 4];
    } else {
        h16* out = (m == 1) ? Bh : (m == 2) ? Dh : Eh;
        h16x8 o0, o1;
#pragma unroll
        for (int j = 0; j < 8; ++j) {
            o0[j] = (h16)tr[wid][r][c0 + j];
            o1[j] = (h16)tr[wid][r][c0 + 8 + j];
        }
        *(h16x8*)&out[(size_t)(row0 + r) * 64 + c0] = o0;
        *(h16x8*)&out[(size_t)(row0 + r) * 64 + c0 + 8] = o1;
    }
}

// ---------------- edge forward (MFMA, persistent, XCD-swizzled) ------------------
// MODE 0: fused edge-embed — A computed from ef/eperm (rank-2 affine), written to
//         ewr (=e_s) for later layers. No e read at all.
// MODE 1: A = e[] + relu(bn(ehat)), write A back to ewr.
// MODE 2: same reconstruction, no write-back (last layer).

template <int MODE>
__global__ void k_edge_fwd(const h16* __restrict__ e, h16* __restrict__ ewr,
                           const float* __restrict__ CW, const float* __restrict__ Cb,
                           const h16* __restrict__ Dh, const h16* __restrict__ Eh,
                           const int* __restrict__ src_s, const int* __restrict__ dst_s,
                           h16* __restrict__ ehat, const float* __restrict__ stats,
                           const float* __restrict__ ef, const int* __restrict__ eperm,
                           const float* __restrict__ eW, const float* __restrict__ eb) {
    __shared__ float tr[4][16][68];
    int lane = threadIdx.x & 63, wid = threadIdx.x >> 6;
    int ar = lane & 15, ak = (lane >> 4) * 8;
    int r = lane >> 2, c0 = (lane & 3) * 16;
    // XCD-aware swizzle: XCD x (= bid%8) owns contiguous block range
    int sb = ((blockIdx.x & 7) << 8) | (blockIdx.x >> 3);   // EF_BLOCKS = 2048
    h16x8 wb0[4], wb1[4];
    float bias[4];
#pragma unroll
    for (int ct = 0; ct < 4; ++ct) {
        int col = ct * 16 + ar;
#pragma unroll
        for (int k = 0; k < 8; ++k) {
            wb0[ct][k] = (h16)CW[(ak + k) * 64 + col];
            wb1[ct][k] = (h16)CW[(32 + ak + k) * 64 + col];
        }
        bias[ct] = Cb[col];
    }
    float sc0[8], sh0[8], sc1[8], sh1[8];       // MODE 1/2: e-BN scale/shift
    float be0[8], w00[8], w10[8], be1[8], w01[8], w11[8];   // MODE 0: embed coeffs
    if (MODE == 0) {
#pragma unroll
        for (int k = 0; k < 8; ++k) {
            int c1 = ak + k, c2 = 32 + ak + k;
            be0[k] = eb[c1]; w00[k] = eW[c1]; w10[k] = eW[64 + c1];
            be1[k] = eb[c2]; w01[k] = eW[c2]; w11[k] = eW[64 + c2];
        }
    } else {
#pragma unroll
        for (int k = 0; k < 8; ++k) {
            sc0[k] = stats[S_ESC + ak + k];      sh0[k] = stats[S_ESH + ak + k];
            sc1[k] = stats[S_ESC + 32 + ak + k]; sh1[k] = stats[S_ESH + 32 + ak + k];
        }
    }
    for (int tile = sb * 4 + wid; tile < NE / 16; tile += EF_BLOCKS * 4) {
        int e0 = tile * 16;
        size_t fbase = (size_t)(e0 + ar) * 64;
        h16x8 a0, a1;
        if (MODE == 0) {
            int ie = eperm[e0 + ar];
            float r0 = 1.0f / ef[ie * 2 + 0];
            float r1 = 1.0f / ef[ie * 2 + 1];
#pragma unroll
            for (int k = 0; k < 8; ++k) {
                a0[k] = (h16)(be0[k] + r0 * w00[k] + r1 * w10[k]);
                a1[k] = (h16)(be1[k] + r0 * w01[k] + r1 * w11[k]);
            }
            *(h16x8*)&ewr[fbase + ak] = a0;       // materialize e_0 for layers 1,2
            *(h16x8*)&ewr[fbase + 32 + ak] = a1;
        } else {
            h16x8 ep0 = *(const h16x8*)&e[fbase + ak];
            h16x8 ep1 = *(const h16x8*)&e[fbase + 32 + ak];
            h16x8 eh0 = *(const h16x8*)&ehat[fbase + ak];
            h16x8 eh1 = *(const h16x8*)&ehat[fbase + 32 + ak];
#pragma unroll
            for (int k = 0; k < 8; ++k) {
                a0[k] = (h16)((float)ep0[k] + fmaxf(0.f, (float)eh0[k] * sc0[k] + sh0[k]));
                a1[k] = (h16)((float)ep1[k] + fmaxf(0.f, (float)eh1[k] * sc1[k] + sh1[k]));
            }
            if (MODE == 1) {
                *(h16x8*)&ewr[fbase + ak] = a0;
                *(h16x8*)&ewr[fbase + 32 + ak] = a1;
            }
        }
        int er = e0 + r;
        int s = src_s[er], d = dst_s[er];   // issue gather indices early
#pragma unroll
        for (int ct = 0; ct < 4; ++ct) {
            float bv = bias[ct];
            f32x4 acc = (f32x4){bv, bv, bv, bv};
            acc = MFMA16(a0, wb0[ct], acc);
            acc = MFMA16(a1, wb1[ct], acc);
#pragma unroll
            for (int j = 0; j < 4; ++j)
                tr[wid][(lane >> 4) * 4 + j][ct * 16 + ar] = acc[j];
        }
        // tr[wid] wave-private: no barrier
        h16x8 d0 = *(const h16x8*)&Dh[(size_t)s * 64 + c0];
        h16x8 d1 = *(const h16x8*)&Dh[(size_t)s * 64 + c0 + 8];
        h16x8 g0 = *(const h16x8*)&Eh[(size_t)d * 64 + c0];
        h16x8 g1 = *(const h16x8*)&Eh[(size_t)d * 64 + c0 + 8];
        h16x8 o0, o1;
#pragma unroll
        for (int j = 0; j < 8; ++j) {
            o0[j] = (h16)(tr[wid][r][c0 + j] + (float)d0[j] + (float)g0[j]);
            o1[j] = (h16)(tr[wid][r][c0 + 8 + j] + (float)d1[j] + (float)g1[j]);
        }
        *(h16x8*)&ehat[(size_t)er * 64 + c0] = o0;
        *(h16x8*)&ehat[(size_t)er * 64 + c0 + 8] = o1;
    }
}

// ---------------- aggregation: contiguous node ranges per wave; banked stats -----

__global__ void k_agg_node(const h16* __restrict__ ehat, const h16* __restrict__ Bh,
                           const int* __restrict__ src_s, const int* __restrict__ rowptr,
                           const float* __restrict__ Ah, float* __restrict__ hnew,
                           float* __restrict__ stats) {
    __shared__ float red[256];
    int lane = threadIdx.x & 63, wid = threadIdx.x >> 6;
    int sb = ((blockIdx.x & 7) << 8) | (blockIdx.x >> 3);   // AGG_BLOCKS = 2048
    int w = sb * 4 + wid;                      // 0..8191; wave owns 4 consecutive nodes
    float esum = 0.f, esq = 0.f, hsum = 0.f, hsq = 0.f;
    int dlo = w * 4;
    for (int d = dlo; d < dlo + 4; ++d) {
        int begin = rowptr[d], end = rowptr[d + 1];
        float accn = 0.f, accd = 0.f;
        int p = begin;
        for (; p + 8 <= end; p += 8) {
            int   ss[8]; float eh[8], bh[8];
#pragma unroll
            for (int q = 0; q < 8; ++q) ss[q] = src_s[p + q];
#pragma unroll
            for (int q = 0; q < 8; ++q) eh[q] = (float)ehat[(size_t)(p + q) * 64 + lane];
#pragma unroll
            for (int q = 0; q < 8; ++q) bh[q] = (float)Bh[(size_t)ss[q] * 64 + lane];
#pragma unroll
            for (int q = 0; q < 8; ++q) {
                float ev = eh[q];
                esum += ev; esq += ev * ev;
                float sg = 1.0f / (1.0f + __expf(-ev));
                accn += sg * bh[q]; accd += sg;
            }
        }
        if (p + 4 <= end) {
            int   ss[4]; float eh[4], bh[4];
#pragma unroll
            for (int q = 0; q < 4; ++q) ss[q] = src_s[p + q];
#pragma unroll
            for (int q = 0; q < 4; ++q) eh[q] = (float)ehat[(size_t)(p + q) * 64 + lane];
#pragma unroll
            for (int q = 0; q < 4; ++q) bh[q] = (float)Bh[(size_t)ss[q] * 64 + lane];
#pragma unroll
            for (int q = 0; q < 4; ++q) {
                float ev = eh[q];
                esum += ev; esq += ev * ev;
                float sg = 1.0f / (1.0f + __expf(-ev));
                accn += sg * bh[q]; accd += sg;
            }
            p += 4;
        }
        for (; p < end; ++p) {
            float ev = (float)ehat[(size_t)p * 64 + lane];
            int s = src_s[p];
            float bv = (float)Bh[(size_t)s * 64 + lane];
            esum += ev; esq += ev * ev;
            float sg = 1.0f / (1.0f + __expf(-ev));
            accn += sg * bv; accd += sg;
        }
        float hv = Ah[(size_t)d * 64 + lane] + accn / (accd + EPS_AGG);
        hnew[(size_t)d * 64 + lane] = hv;
        hsum += hv; hsq += hv * hv;
    }
    float vals[4] = {esum, esq, hsum, hsq};
    int bank = blockIdx.x & (NBANK - 1);
#pragma unroll
    for (int s2 = 0; s2 < 4; ++s2) {
        red[wid * 64 + lane] = vals[s2];
        __syncthreads();
        if (wid == 0)
            atomicAdd(&stats[bank * 256 + s2 * 64 + lane],
                      red[lane] + red[64 + lane] + red[128 + lane] + red[192 + lane]);
        __syncthreads();
    }
}

// ---------------- finalize BN stats (sum banks) -> scale/shift; re-zero ----------

__global__ void k_finstats2(float* __restrict__ stats, const float* __restrict__ eg,
                            const float* __restrict__ eb, const float* __restrict__ hgm,
                            const float* __restrict__ hbt) {
    int t = threadIdx.x;  // 128
    float s1 = 0.f, s2 = 0.f;
    if (t < 64) {
#pragma unroll
        for (int b = 0; b < NBANK; ++b) {
            s1 += stats[b * 256 + t];
            s2 += stats[b * 256 + 64 + t];
        }
    } else {
        int j = t - 64;
#pragma unroll
        for (int b = 0; b < NBANK; ++b) {
            s1 += stats[b * 256 + 128 + j];
            s2 += stats[b * 256 + 192 + j];
        }
    }
    float o1, o2; int i1, i2;
    if (t < 64) {
        float mu = s1 / (float)NE;
        float var = s2 / (float)NE - mu * mu;
        float rs = rsqrtf(var + EPS_BN);
        float g = eg[t];
        o1 = g * rs; o2 = eb[t] - g * mu * rs;
        i1 = S_ESC + t; i2 = S_ESH + t;
    } else {
        int j = t - 64;
        float mu = s1 / (float)NN;
        float var = s2 / (float)NN - mu * mu;
        float rs = rsqrtf(var + EPS_BN);
        float g = hgm[j];
        o1 = g * rs; o2 = hbt[j] - g * mu * rs;
        i1 = S_HSC + j; i2 = S_HSH + j;
    }
    __syncthreads();
    for (int i = t; i < NBANK * 256; i += 128) stats[i] = 0.f;  // re-zero accumulators
    stats[i1] = o1; stats[i2] = o2;
}

// ---------------- h BN apply ----------------

__global__ void k_hbn_apply(float* __restrict__ h, h16* __restrict__ h16buf,
                            const float* __restrict__ hnew,
                            const float* __restrict__ stats) {
    int t = blockIdx.x * blockDim.x + threadIdx.x;  // NN*16
    int j4 = t & 15;
    float4 s = ((const float4*)(stats + S_HSC))[j4];
    float4 b = ((const float4*)(stats + S_HSH))[j4];
    float4 v = ((const float4*)hnew)[t];
    float4 x = ((const float4*)h)[t];
    x.x += fmaxf(0.f, v.x * s.x + b.x);
    x.y += fmaxf(0.f, v.y * s.y + b.y);
    x.z += fmaxf(0.f, v.z * s.z + b.z);
    x.w += fmaxf(0.f, v.w * s.w + b.w);
    ((float4*)h)[t] = x;
    h16x4 o;
    o[0] = (h16)x.x; o[1] = (h16)x.y; o[2] = (h16)x.z; o[3] = (h16)x.w;
    *(h16x4*)&h16buf[(size_t)t * 4] = o;
}

// ---------------- readout: wave per graph (gid sorted, no atomics) ----------------

__global__ void k_graph_mean(const float* __restrict__ h, const int* __restrict__ grp,
                             float* __restrict__ hg) {
    int lane = threadIdx.x & 63, wid = threadIdx.x >> 6;
    int g = blockIdx.x * 4 + wid;   // NB/4 blocks
    int begin = grp[g], end = grp[g + 1];
    float acc = 0.f;
    int i = begin;
    for (; i + 4 <= end; i += 4) {
        float a0 = h[(size_t)(i + 0) * 64 + lane];
        float a1 = h[(size_t)(i + 1) * 64 + lane];
        float a2 = h[(size_t)(i + 2) * 64 + lane];
        float a3 = h[(size_t)(i + 3) * 64 + lane];
        acc += (a0 + a1) + (a2 + a3);
    }
    for (; i < end; ++i) acc += h[(size_t)i * 64 + lane];
    float cnt = (float)(end - begin);
    hg[g * 64 + lane] = acc / fmaxf(cnt, 1.0f);
}

// ---------------- fused MLP: l1 -> l2 -> l3 in one kernel, one block per graph ----

__global__ void k_mlp(const float* __restrict__ hg, const float* __restrict__ st,
                      const float* __restrict__ ac,
                      const float* __restrict__ W1, const float* __restrict__ b1,
                      const float* __restrict__ W2, const float* __restrict__ b2,
                      const float* __restrict__ W3, const float* __restrict__ b3,
                      float* __restrict__ out) {
    __shared__ float xin[88];
    __shared__ float y[256];
    __shared__ float red4[4];
    int g = blockIdx.x, t = threadIdx.x;
    if (t < 64) xin[t] = hg[g * 64 + t];
    else if (t < 80) xin[t] = st[g * 16 + (t - 64)];
    else if (t < 82) xin[t] = ac[g * 2 + (t - 80)];
    __syncthreads();
    float acc = b1[t];
#pragma unroll 2
    for (int k = 0; k < 82; ++k) acc += xin[k] * W1[k * 256 + t];
    y[t] = fmaxf(acc, 0.f);
    __syncthreads();
    acc = b2[t];
#pragma unroll 8
    for (int k = 0; k < 256; ++k) acc += y[k] * W2[k * 256 + t];
    float xv = fmaxf(acc, 0.f);
    float p = xv * W3[t];
#pragma unroll
    for (int o = 32; o > 0; o >>= 1) p += __shfl_down(p, o);
    if ((t & 63) == 0) red4[t >> 6] = p;
    __syncthreads();
    if (t == 0) out[g] = red4[0] + red4[1] + red4[2] + red4[3] + b3[0];
}

// ---------------- launch ----------------

extern "C" void kernel_launch(void* const* d_in, const int* in_sizes, int n_in,
                              void* d_out, int out_size, void* d_ws, size_t ws_size,
                              hipStream_t stream) {
    const float* in_h   = (const float*)d_in[0];
    const float* e_feat = (const float*)d_in[1];
    const int*   src    = (const int*)d_in[2];
    const int*   dst    = (const int*)d_in[3];
    const int*   gid    = (const int*)d_in[4];
    const float* state  = (const float*)d_in[5];
    const float* action = (const float*)d_in[6];
    const float* embhW  = (const float*)d_in[7];
    const float* embhb  = (const float*)d_in[8];
    const float* embeW  = (const float*)d_in[9];
    const float* embeb  = (const float*)d_in[10];
    const float* A_W = (const float*)d_in[11]; const float* A_b = (const float*)d_in[12];
    const float* B_W = (const float*)d_in[13]; const float* B_b = (const float*)d_in[14];
    const float* C_W = (const float*)d_in[15]; const float* C_b = (const float*)d_in[16];
    const float* D_W = (const float*)d_in[17]; const float* D_b = (const float*)d_in[18];
    const float* E_W = (const float*)d_in[19]; const float* E_b = (const float*)d_in[20];
    const float* bnhg = (const float*)d_in[21]; const float* bnhb = (const float*)d_in[22];
    const float* bneg = (const float*)d_in[23]; const float* bneb = (const float*)d_in[24];
    const float* l1W = (const float*)d_in[25]; const float* l1b = (const float*)d_in[26];
    const float* l2W = (const float*)d_in[27]; const float* l2b = (const float*)d_in[28];
    const float* l3W = (const float*)d_in[29]; const float* l3b = (const float*)d_in[30];

    char* base = (char*)d_ws;
    size_t off = 0;
    auto alloc = [&](size_t bytes) {
        off = (off + 255) & ~(size_t)255;
        void* p = base + off; off += bytes; return p;
    };
    h16*   e_s    = (h16*)  alloc((size_t)NE * 64 * 2);
    h16*   ehat   = (h16*)  alloc((size_t)NE * 64 * 2);
    float* h      = (float*)alloc((size_t)NN * 64 * 4);
    h16*   h16buf = (h16*)  alloc((size_t)NN * 64 * 2);
    float* Ah     = (float*)alloc((size_t)NN * 64 * 4);
    float* hnew   = (float*)alloc((size_t)NN * 64 * 4);
    h16*   Bh     = (h16*)  alloc((size_t)NN * 64 * 2);
    h16*   Dh     = (h16*)  alloc((size_t)NN * 64 * 2);
    h16*   Eh     = (h16*)  alloc((size_t)NN * 64 * 2);
    float* stats  = (float*)alloc((NBANK * 256 + 512) * 4);
    float* hg     = (float*)alloc((size_t)NB * 64 * 4);
    int*   eperm  = (int*)  alloc((size_t)NE * 4);
    int*   src_s  = (int*)  alloc((size_t)NE * 4);
    int*   dst_s  = (int*)  alloc((size_t)NE * 4);
    int*   hist   = (int*)  alloc((size_t)NN * 4);   // NN*4 is 256B-aligned size
    int*   ghist  = (int*)  alloc(256 * 4);          // contiguous with hist
    int*   rowptr = (int*)  alloc((size_t)(NN + 1) * 4);
    int*   cursor = (int*)  alloc((size_t)NN * 4);
    int*   grp    = (int*)  alloc((size_t)(NB + 1) * 4);
    size_t need = off;

    if (ws_size < need) return;  // fail validation rather than fault

    // ---- CSR build (dst-sorted edge order) + graph rowptr ----
    k_zero4<<<33, 256, 0, stream>>>((float4*)hist, ((long)NN * 4 + 256 * 4) / 16);
    k_hist<<<NE / 256, 256, 0, stream>>>(dst, hist);
    k_scan<<<1, 1024, 0, stream>>>(hist, rowptr, cursor);
    k_scatter<<<NE / 256, 256, 0, stream>>>(src, dst, cursor, eperm, src_s, dst_s);
    k_ghist<<<NN / 256, 256, 0, stream>>>(gid, ghist);
    k_gscan<<<1, 256, 0, stream>>>(ghist, grp);

    // ---- node embedding ----
    k_embed_h<<<(NN * 64) / 256, 256, 0, stream>>>(in_h, embhW, embhb, h, h16buf);

    k_zero4<<<4, 256, 0, stream>>>((float4*)stats, (NBANK * 256) / 4);  // zero banks once
    for (int l = 0; l < NL; ++l) {
        k_node_gemm<<<NG_BLOCKS, 256, 0, stream>>>(h16buf,
                                                   A_W + l * 4096, A_b + l * 64,
                                                   B_W + l * 4096, B_b + l * 64,
                                                   D_W + l * 4096, D_b + l * 64,
                                                   E_W + l * 4096, E_b + l * 64,
                                                   Ah, Bh, Dh, Eh);
        if (l == 0)
            k_edge_fwd<0><<<EF_BLOCKS, 256, 0, stream>>>(e_s, e_s,
                C_W + l * 4096, C_b + l * 64, Dh, Eh, src_s, dst_s, ehat, stats,
                e_feat, eperm, embeW, embeb);
        else if (l == 1)
            k_edge_fwd<1><<<EF_BLOCKS, 256, 0, stream>>>(e_s, e_s,
                C_W + l * 4096, C_b + l * 64, Dh, Eh, src_s, dst_s, ehat, stats,
                e_feat, eperm, embeW, embeb);
        else
            k_edge_fwd<2><<<EF_BLOCKS, 256, 0, stream>>>(e_s, nullptr,
                C_W + l * 4096, C_b + l * 64, Dh, Eh, src_s, dst_s, ehat, stats,
                e_feat, eperm, embeW, embeb);
        k_agg_node<<<AGG_BLOCKS, 256, 0, stream>>>(ehat, Bh, src_s, rowptr, Ah, hnew, stats);
        k_finstats2<<<1, 128, 0, stream>>>(stats, bneg + l * 64, bneb + l * 64,
                                           bnhg + l * 64, bnhb + l * 64);
        k_hbn_apply<<<NN / 16, 256, 0, stream>>>(h, h16buf, hnew, stats);
    }

    // ---- readout (atomic-free) ----
    k_graph_mean<<<NB / 4, 256, 0, stream>>>(h, grp, hg);

    // ---- fused MLP ----
    k_mlp<<<NB, 256, 0, stream>>>(hg, state, action, l1W, l1b, l2W, l2b, l3W, l3b,
                                  (float*)d_out);
}

// Round 16
// 495.343 us; speedup vs baseline: 1.0393x; 1.0393x over previous
//
#include <hip/hip_runtime.h>
#include <math.h>

#define NN 32768       // nodes
#define NE 524288      // edges
#define NB 256         // graphs/batch
#define HID 64
#define NL 3
#define EPS_AGG 1e-6f
#define EPS_BN 1e-5f
#define AGG_BLOCKS 2048
#define EF_BLOCKS 2048
#define NG_BLOCKS 2048
#define NBANK 16
// stats layout: [0 .. NBANK*256) banked accumulators {esum,esq,hsum,hsq}x64
// [4096..4159] e-scale  [4160..4223] e-shift  [4224..4287] h-scale  [4288..4351] h-shift
#define S_ESC 4096
#define S_ESH 4160
#define S_HSC 4224
#define S_HSH 4288

typedef _Float16 h16;
typedef h16 h16x8 __attribute__((ext_vector_type(8)));
typedef h16 h16x4 __attribute__((ext_vector_type(4)));
typedef float f32x4 __attribute__((ext_vector_type(4)));

#define MFMA16(a, b, c) __builtin_amdgcn_mfma_f32_16x16x32_f16(a, b, c, 0, 0, 0)

// ---------------- utility ----------------

__global__ void k_zero4(float4* __restrict__ p, long n4) {
    long t = (long)blockIdx.x * blockDim.x + threadIdx.x;
    long stride = (long)gridDim.x * blockDim.x;
    float4 z = {0.f, 0.f, 0.f, 0.f};
    for (; t < n4; t += stride) p[t] = z;
}

// ---------------- CSR build (counting sort by dst) ----------------

__global__ void k_hist(const int* __restrict__ dst, int* __restrict__ hist) {
    int i = blockIdx.x * blockDim.x + threadIdx.x;   // NE threads
    atomicAdd(&hist[dst[i]], 1);
}

__global__ void k_scan(const int* __restrict__ hist, int* __restrict__ rowptr,
                       int* __restrict__ cursor) {
    __shared__ int part[1024];
    int t = threadIdx.x;
    int loc[32];
    int base = t * 32, sum = 0;
#pragma unroll
    for (int k = 0; k < 32; ++k) { loc[k] = hist[base + k]; sum += loc[k]; }
    part[t] = sum;
    __syncthreads();
    for (int off = 1; off < 1024; off <<= 1) {
        int v = (t >= off) ? part[t - off] : 0;
        __syncthreads();
        part[t] += v;
        __syncthreads();
    }
    int ex = part[t] - sum;
#pragma unroll
    for (int k = 0; k < 32; ++k) {
        rowptr[base + k] = ex; cursor[base + k] = ex; ex += loc[k];
    }
    if (t == 1023) rowptr[NN] = ex;
}

__global__ void k_scatter(const int* __restrict__ src, const int* __restrict__ dst,
                          int* __restrict__ cursor, int* __restrict__ eperm,
                          int* __restrict__ src_s, int* __restrict__ dst_s) {
    int i = blockIdx.x * blockDim.x + threadIdx.x;   // NE threads
    int d = dst[i];
    int pos = atomicAdd(&cursor[d], 1);
    eperm[pos] = i;
    src_s[pos] = src[i];
    dst_s[pos] = d;
}

// ---------------- graph rowptr (gid is sorted) ----------------

__global__ void k_ghist(const int* __restrict__ gid, int* __restrict__ ghist) {
    int i = blockIdx.x * blockDim.x + threadIdx.x;   // NN threads
    atomicAdd(&ghist[gid[i]], 1);
}

__global__ void k_gscan(const int* __restrict__ ghist, int* __restrict__ grp) {
    __shared__ int part[256];
    int t = threadIdx.x;   // 256
    int v = ghist[t];
    part[t] = v;
    __syncthreads();
    for (int off = 1; off < 256; off <<= 1) {
        int u = (t >= off) ? part[t - off] : 0;
        __syncthreads();
        part[t] += u;
        __syncthreads();
    }
    grp[t + 1] = part[t];
    if (t == 0) grp[0] = 0;
}

// ---------------- embeddings ----------------

__global__ void k_embed_h(const float* __restrict__ hin, const float* __restrict__ W,
                          const float* __restrict__ b, float* __restrict__ out,
                          h16* __restrict__ out16) {
    int tid = blockIdx.x * blockDim.x + threadIdx.x;   // NN*64 threads
    int i = tid >> 6, j = tid & 63;
    float acc = b[j];
#pragma unroll
    for (int k = 0; k < 6; ++k) acc += hin[i * 6 + k] * W[k * 64 + j];
    out[tid] = acc;
    out16[tid] = (h16)acc;
}

// vectorized: 1 thread = 8 columns of one (permuted) edge, h16x8 store
__global__ void k_embed_e_perm(const float* __restrict__ ef, const int* __restrict__ eperm,
                               const float* __restrict__ W, const float* __restrict__ b,
                               h16* __restrict__ out) {
    int t = blockIdx.x * blockDim.x + threadIdx.x;   // NE*8 threads
    int pos = t >> 3, j0 = (t & 7) * 8;
    int i = eperm[pos];
    float r0 = 1.0f / ef[i * 2 + 0];
    float r1 = 1.0f / ef[i * 2 + 1];
    float4 b0 = *(const float4*)&b[j0],      b1 = *(const float4*)&b[j0 + 4];
    float4 w00 = *(const float4*)&W[j0],     w01 = *(const float4*)&W[j0 + 4];
    float4 w10 = *(const float4*)&W[64 + j0], w11 = *(const float4*)&W[64 + j0 + 4];
    h16x8 o;
    o[0] = (h16)(b0.x + r0 * w00.x + r1 * w10.x);
    o[1] = (h16)(b0.y + r0 * w00.y + r1 * w10.y);
    o[2] = (h16)(b0.z + r0 * w00.z + r1 * w10.z);
    o[3] = (h16)(b0.w + r0 * w00.w + r1 * w10.w);
    o[4] = (h16)(b1.x + r0 * w01.x + r1 * w11.x);
    o[5] = (h16)(b1.y + r0 * w01.y + r1 * w11.y);
    o[6] = (h16)(b1.z + r0 * w01.z + r1 * w11.z);
    o[7] = (h16)(b1.w + r0 * w01.w + r1 * w11.w);
    *(h16x8*)&out[(size_t)pos * 64 + j0] = o;
}

// ---------------- node GEMM (MFMA): one wave per (tile, matrix) -----------------

__global__ void k_node_gemm(const h16* __restrict__ X,
                            const float* __restrict__ AW, const float* __restrict__ Ab,
                            const float* __restrict__ BW, const float* __restrict__ Bb,
                            const float* __restrict__ DW, const float* __restrict__ Db,
                            const float* __restrict__ EW, const float* __restrict__ Eb,
                            float* __restrict__ Ah, h16* __restrict__ Bh,
                            h16* __restrict__ Dh, h16* __restrict__ Eh) {
    __shared__ float tr[4][16][68];
    int lane = threadIdx.x & 63, wid = threadIdx.x >> 6;
    int wg = blockIdx.x * 4 + wid;            // 0..8191
    int m = wg & 3, tile = wg >> 2;           // tile < NN/16
    int ar = lane & 15, ak = (lane >> 4) * 8;
    int r = lane >> 2, c0 = (lane & 3) * 16;
    const float* W  = (m == 0) ? AW : (m == 1) ? BW : (m == 2) ? DW : EW;
    const float* Bb_ = (m == 0) ? Ab : (m == 1) ? Bb : (m == 2) ? Db : Eb;
    h16x8 wb0[4], wb1[4];
    float bias[4];
#pragma unroll
    for (int ct = 0; ct < 4; ++ct) {
        int col = ct * 16 + ar;
#pragma unroll
        for (int k = 0; k < 8; ++k) {
            wb0[ct][k] = (h16)W[(ak + k) * 64 + col];
            wb1[ct][k] = (h16)W[(32 + ak + k) * 64 + col];
        }
        bias[ct] = Bb_[col];
    }
    int row0 = tile * 16;
    h16x8 a0 = *(const h16x8*)&X[(size_t)(row0 + ar) * 64 + ak];
    h16x8 a1 = *(const h16x8*)&X[(size_t)(row0 + ar) * 64 + 32 + ak];
#pragma unroll
    for (int ct = 0; ct < 4; ++ct) {
        float bv = bias[ct];
        f32x4 acc = (f32x4){bv, bv, bv, bv};
        acc = MFMA16(a0, wb0[ct], acc);
        acc = MFMA16(a1, wb1[ct], acc);
#pragma unroll
        for (int j = 0; j < 4; ++j)
            tr[wid][(lane >> 4) * 4 + j][ct * 16 + ar] = acc[j];
    }
    // tr[wid] wave-private: no barrier
    if (m == 0) {
#pragma unroll
        for (int j = 0; j < 4; ++j)
            *(float4*)&Ah[(size_t)(row0 + r) * 64 + c0 + j * 4] =
                *(float4*)&tr[wid][r][c0 + j * 4];
    } else {
        h16* out = (m == 1) ? Bh : (m == 2) ? Dh : Eh;
        h16x8 o0, o1;
#pragma unroll
        for (int j = 0; j < 8; ++j) {
            o0[j] = (h16)tr[wid][r][c0 + j];
            o1[j] = (h16)tr[wid][r][c0 + 8 + j];
        }
        *(h16x8*)&out[(size_t)(row0 + r) * 64 + c0] = o0;
        *(h16x8*)&out[(size_t)(row0 + r) * 64 + c0 + 8] = o1;
    }
}

// ---------------- edge forward (MFMA, persistent, XCD-swizzled) ------------------
// MODE 0: A = e[]; MODE 1: A = e[] + relu(bn(ehat)), write-back; MODE 2: no wb.

template <int MODE>
__global__ void k_edge_fwd(const h16* __restrict__ e, h16* __restrict__ ewr,
                           const float* __restrict__ CW, const float* __restrict__ Cb,
                           const h16* __restrict__ Dh, const h16* __restrict__ Eh,
                           const int* __restrict__ src_s, const int* __restrict__ dst_s,
                           h16* __restrict__ ehat, const float* __restrict__ stats) {
    __shared__ float tr[4][16][68];
    int lane = threadIdx.x & 63, wid = threadIdx.x >> 6;
    int ar = lane & 15, ak = (lane >> 4) * 8;
    int r = lane >> 2, c0 = (lane & 3) * 16;
    // XCD-aware swizzle: XCD x (= bid%8) owns contiguous block range
    int sb = ((blockIdx.x & 7) << 8) | (blockIdx.x >> 3);   // EF_BLOCKS = 2048
    h16x8 wb0[4], wb1[4];
    float bias[4];
#pragma unroll
    for (int ct = 0; ct < 4; ++ct) {
        int col = ct * 16 + ar;
#pragma unroll
        for (int k = 0; k < 8; ++k) {
            wb0[ct][k] = (h16)CW[(ak + k) * 64 + col];
            wb1[ct][k] = (h16)CW[(32 + ak + k) * 64 + col];
        }
        bias[ct] = Cb[col];
    }
    float sc0[8], sh0[8], sc1[8], sh1[8];
    if (MODE != 0) {
#pragma unroll
        for (int k = 0; k < 8; ++k) {
            sc0[k] = stats[S_ESC + ak + k];      sh0[k] = stats[S_ESH + ak + k];
            sc1[k] = stats[S_ESC + 32 + ak + k]; sh1[k] = stats[S_ESH + 32 + ak + k];
        }
    }
    for (int tile = sb * 4 + wid; tile < NE / 16; tile += EF_BLOCKS * 4) {
        int e0 = tile * 16;
        size_t fbase = (size_t)(e0 + ar) * 64;
        h16x8 a0, a1;
        if (MODE == 0) {
            a0 = *(const h16x8*)&e[fbase + ak];
            a1 = *(const h16x8*)&e[fbase + 32 + ak];
        } else {
            h16x8 ep0 = *(const h16x8*)&e[fbase + ak];
            h16x8 ep1 = *(const h16x8*)&e[fbase + 32 + ak];
            h16x8 eh0 = *(const h16x8*)&ehat[fbase + ak];
            h16x8 eh1 = *(const h16x8*)&ehat[fbase + 32 + ak];
#pragma unroll
            for (int k = 0; k < 8; ++k) {
                a0[k] = (h16)((float)ep0[k] + fmaxf(0.f, (float)eh0[k] * sc0[k] + sh0[k]));
                a1[k] = (h16)((float)ep1[k] + fmaxf(0.f, (float)eh1[k] * sc1[k] + sh1[k]));
            }
            if (MODE == 1) {
                *(h16x8*)&ewr[fbase + ak] = a0;
                *(h16x8*)&ewr[fbase + 32 + ak] = a1;
            }
        }
        int er = e0 + r;
        int s = src_s[er], d = dst_s[er];   // issue gather indices early
#pragma unroll
        for (int ct = 0; ct < 4; ++ct) {
            float bv = bias[ct];
            f32x4 acc = (f32x4){bv, bv, bv, bv};
            acc = MFMA16(a0, wb0[ct], acc);
            acc = MFMA16(a1, wb1[ct], acc);
#pragma unroll
            for (int j = 0; j < 4; ++j)
                tr[wid][(lane >> 4) * 4 + j][ct * 16 + ar] = acc[j];
        }
        // tr[wid] wave-private: no barrier
        h16x8 d0 = *(const h16x8*)&Dh[(size_t)s * 64 + c0];
        h16x8 d1 = *(const h16x8*)&Dh[(size_t)s * 64 + c0 + 8];
        h16x8 g0 = *(const h16x8*)&Eh[(size_t)d * 64 + c0];
        h16x8 g1 = *(const h16x8*)&Eh[(size_t)d * 64 + c0 + 8];
        h16x8 o0, o1;
#pragma unroll
        for (int j = 0; j < 8; ++j) {
            o0[j] = (h16)(tr[wid][r][c0 + j] + (float)d0[j] + (float)g0[j]);
            o1[j] = (h16)(tr[wid][r][c0 + 8 + j] + (float)d1[j] + (float)g1[j]);
        }
        *(h16x8*)&ehat[(size_t)er * 64 + c0] = o0;
        *(h16x8*)&ehat[(size_t)er * 64 + c0 + 8] = o1;
    }
}

// ---------------- aggregation: full-occupancy grid-stride; banked stats ----------

__global__ void k_agg_node(const h16* __restrict__ ehat, const h16* __restrict__ Bh,
                           const int* __restrict__ src_s, const int* __restrict__ rowptr,
                           const float* __restrict__ Ah, float* __restrict__ hnew,
                           float* __restrict__ stats) {
    __shared__ float red[256];
    int lane = threadIdx.x & 63, wid = threadIdx.x >> 6;
    int wglob = blockIdx.x * 4 + wid;          // 0 .. AGG_BLOCKS*4-1
    float esum = 0.f, esq = 0.f, hsum = 0.f, hsq = 0.f;
    for (int d = wglob; d < NN; d += AGG_BLOCKS * 4) {
        int begin = rowptr[d], end = rowptr[d + 1];
        float accn = 0.f, accd = 0.f;
        int p = begin;
        for (; p + 8 <= end; p += 8) {
            int   ss[8]; float eh[8], bh[8];
#pragma unroll
            for (int q = 0; q < 8; ++q) ss[q] = src_s[p + q];
#pragma unroll
            for (int q = 0; q < 8; ++q) eh[q] = (float)ehat[(size_t)(p + q) * 64 + lane];
#pragma unroll
            for (int q = 0; q < 8; ++q) bh[q] = (float)Bh[(size_t)ss[q] * 64 + lane];
#pragma unroll
            for (int q = 0; q < 8; ++q) {
                float ev = eh[q];
                esum += ev; esq += ev * ev;
                float sg = 1.0f / (1.0f + __expf(-ev));
                accn += sg * bh[q]; accd += sg;
            }
        }
        if (p + 4 <= end) {
            int   ss[4]; float eh[4], bh[4];
#pragma unroll
            for (int q = 0; q < 4; ++q) ss[q] = src_s[p + q];
#pragma unroll
            for (int q = 0; q < 4; ++q) eh[q] = (float)ehat[(size_t)(p + q) * 64 + lane];
#pragma unroll
            for (int q = 0; q < 4; ++q) bh[q] = (float)Bh[(size_t)ss[q] * 64 + lane];
#pragma unroll
            for (int q = 0; q < 4; ++q) {
                float ev = eh[q];
                esum += ev; esq += ev * ev;
                float sg = 1.0f / (1.0f + __expf(-ev));
                accn += sg * bh[q]; accd += sg;
            }
            p += 4;
        }
        for (; p < end; ++p) {
            float ev = (float)ehat[(size_t)p * 64 + lane];
            int s = src_s[p];
            float bv = (float)Bh[(size_t)s * 64 + lane];
            esum += ev; esq += ev * ev;
            float sg = 1.0f / (1.0f + __expf(-ev));
            accn += sg * bv; accd += sg;
        }
        float hv = Ah[(size_t)d * 64 + lane] + accn / (accd + EPS_AGG);
        hnew[(size_t)d * 64 + lane] = hv;
        hsum += hv; hsq += hv * hv;
    }
    float vals[4] = {esum, esq, hsum, hsq};
    int bank = blockIdx.x & (NBANK - 1);
#pragma unroll
    for (int s2 = 0; s2 < 4; ++s2) {
        red[wid * 64 + lane] = vals[s2];
        __syncthreads();
        if (wid == 0)
            atomicAdd(&stats[bank * 256 + s2 * 64 + lane],
                      red[lane] + red[64 + lane] + red[128 + lane] + red[192 + lane]);
        __syncthreads();
    }
}

// ---------------- finalize BN stats (sum banks) -> scale/shift; re-zero ----------

__global__ void k_finstats2(float* __restrict__ stats, const float* __restrict__ eg,
                            const float* __restrict__ eb, const float* __restrict__ hgm,
                            const float* __restrict__ hbt) {
    int t = threadIdx.x;  // 128
    float s1 = 0.f, s2 = 0.f;
    if (t < 64) {
#pragma unroll
        for (int b = 0; b < NBANK; ++b) {
            s1 += stats[b * 256 + t];
            s2 += stats[b * 256 + 64 + t];
        }
    } else {
        int j = t - 64;
#pragma unroll
        for (int b = 0; b < NBANK; ++b) {
            s1 += stats[b * 256 + 128 + j];
            s2 += stats[b * 256 + 192 + j];
        }
    }
    float o1, o2; int i1, i2;
    if (t < 64) {
        float mu = s1 / (float)NE;
        float var = s2 / (float)NE - mu * mu;
        float rs = rsqrtf(var + EPS_BN);
        float g = eg[t];
        o1 = g * rs; o2 = eb[t] - g * mu * rs;
        i1 = S_ESC + t; i2 = S_ESH + t;
    } else {
        int j = t - 64;
        float mu = s1 / (float)NN;
        float var = s2 / (float)NN - mu * mu;
        float rs = rsqrtf(var + EPS_BN);
        float g = hgm[j];
        o1 = g * rs; o2 = hbt[j] - g * mu * rs;
        i1 = S_HSC + j; i2 = S_HSH + j;
    }
    __syncthreads();
    for (int i = t; i < NBANK * 256; i += 128) stats[i] = 0.f;  // re-zero accumulators
    stats[i1] = o1; stats[i2] = o2;
}

// ---------------- h BN apply ----------------

__global__ void k_hbn_apply(float* __restrict__ h, h16* __restrict__ h16buf,
                            const float* __restrict__ hnew,
                            const float* __restrict__ stats) {
    int t = blockIdx.x * blockDim.x + threadIdx.x;  // NN*16
    int j4 = t & 15;
    float4 s = ((const float4*)(stats + S_HSC))[j4];
    float4 b = ((const float4*)(stats + S_HSH))[j4];
    float4 v = ((const float4*)hnew)[t];
    float4 x = ((const float4*)h)[t];
    x.x += fmaxf(0.f, v.x * s.x + b.x);
    x.y += fmaxf(0.f, v.y * s.y + b.y);
    x.z += fmaxf(0.f, v.z * s.z + b.z);
    x.w += fmaxf(0.f, v.w * s.w + b.w);
    ((float4*)h)[t] = x;
    h16x4 o;
    o[0] = (h16)x.x; o[1] = (h16)x.y; o[2] = (h16)x.z; o[3] = (h16)x.w;
    *(h16x4*)&h16buf[(size_t)t * 4] = o;
}

// ---------------- readout: wave per graph (gid sorted, no atomics) ----------------

__global__ void k_graph_mean(const float* __restrict__ h, const int* __restrict__ grp,
                             float* __restrict__ hg) {
    int lane = threadIdx.x & 63, wid = threadIdx.x >> 6;
    int g = blockIdx.x * 4 + wid;   // NB/4 blocks
    int begin = grp[g], end = grp[g + 1];
    float acc = 0.f;
    int i = begin;
    for (; i + 4 <= end; i += 4) {
        float a0 = h[(size_t)(i + 0) * 64 + lane];
        float a1 = h[(size_t)(i + 1) * 64 + lane];
        float a2 = h[(size_t)(i + 2) * 64 + lane];
        float a3 = h[(size_t)(i + 3) * 64 + lane];
        acc += (a0 + a1) + (a2 + a3);
    }
    for (; i < end; ++i) acc += h[(size_t)i * 64 + lane];
    float cnt = (float)(end - begin);
    hg[g * 64 + lane] = acc / fmaxf(cnt, 1.0f);
}

// ---------------- fused MLP: l1 -> l2 -> l3 in one kernel, one block per graph ----

__global__ void k_mlp(const float* __restrict__ hg, const float* __restrict__ st,
                      const float* __restrict__ ac,
                      const float* __restrict__ W1, const float* __restrict__ b1,
                      const float* __restrict__ W2, const float* __restrict__ b2,
                      const float* __restrict__ W3, const float* __restrict__ b3,
                      float* __restrict__ out) {
    __shared__ float xin[88];
    __shared__ float y[256];
    __shared__ float red4[4];
    int g = blockIdx.x, t = threadIdx.x;
    if (t < 64) xin[t] = hg[g * 64 + t];
    else if (t < 80) xin[t] = st[g * 16 + (t - 64)];
    else if (t < 82) xin[t] = ac[g * 2 + (t - 80)];
    __syncthreads();
    float acc = b1[t];
#pragma unroll 2
    for (int k = 0; k < 82; ++k) acc += xin[k] * W1[k * 256 + t];
    y[t] = fmaxf(acc, 0.f);
    __syncthreads();
    acc = b2[t];
#pragma unroll 8
    for (int k = 0; k < 256; ++k) acc += y[k] * W2[k * 256 + t];
    float xv = fmaxf(acc, 0.f);
    float p = xv * W3[t];
#pragma unroll
    for (int o = 32; o > 0; o >>= 1) p += __shfl_down(p, o);
    if ((t & 63) == 0) red4[t >> 6] = p;
    __syncthreads();
    if (t == 0) out[g] = red4[0] + red4[1] + red4[2] + red4[3] + b3[0];
}

// ---------------- launch ----------------

extern "C" void kernel_launch(void* const* d_in, const int* in_sizes, int n_in,
                              void* d_out, int out_size, void* d_ws, size_t ws_size,
                              hipStream_t stream) {
    const float* in_h   = (const float*)d_in[0];
    const float* e_feat = (const float*)d_in[1];
    const int*   src    = (const int*)d_in[2];
    const int*   dst    = (const int*)d_in[3];
    const int*   gid    = (const int*)d_in[4];
    const float* state  = (const float*)d_in[5];
    const float* action = (const float*)d_in[6];
    const float* embhW  = (const float*)d_in[7];
    const float* embhb  = (const float*)d_in[8];
    const float* embeW  = (const float*)d_in[9];
    const float* embeb  = (const float*)d_in[10];
    const float* A_W = (const float*)d_in[11]; const float* A_b = (const float*)d_in[12];
    const float* B_W = (const float*)d_in[13]; const float* B_b = (const float*)d_in[14];
    const float* C_W = (const float*)d_in[15]; const float* C_b = (const float*)d_in[16];
    const float* D_W = (const float*)d_in[17]; const float* D_b = (const float*)d_in[18];
    const float* E_W = (const float*)d_in[19]; const float* E_b = (const float*)d_in[20];
    const float* bnhg = (const float*)d_in[21]; const float* bnhb = (const float*)d_in[22];
    const float* bneg = (const float*)d_in[23]; const float* bneb = (const float*)d_in[24];
    const float* l1W = (const float*)d_in[25]; const float* l1b = (const float*)d_in[26];
    const float* l2W = (const float*)d_in[27]; const float* l2b = (const float*)d_in[28];
    const float* l3W = (const float*)d_in[29]; const float* l3b = (const float*)d_in[30];

    char* base = (char*)d_ws;
    size_t off = 0;
    auto alloc = [&](size_t bytes) {
        off = (off + 255) & ~(size_t)255;
        void* p = base + off; off += bytes; return p;
    };
    h16*   e_s    = (h16*)  alloc((size_t)NE * 64 * 2);
    h16*   ehat   = (h16*)  alloc((size_t)NE * 64 * 2);
    float* h      = (float*)alloc((size_t)NN * 64 * 4);
    h16*   h16buf = (h16*)  alloc((size_t)NN * 64 * 2);
    float* Ah     = (float*)alloc((size_t)NN * 64 * 4);
    float* hnew   = (float*)alloc((size_t)NN * 64 * 4);
    h16*   Bh     = (h16*)  alloc((size_t)NN * 64 * 2);
    h16*   Dh     = (h16*)  alloc((size_t)NN * 64 * 2);
    h16*   Eh     = (h16*)  alloc((size_t)NN * 64 * 2);
    float* stats  = (float*)alloc((NBANK * 256 + 512) * 4);
    float* hg     = (float*)alloc((size_t)NB * 64 * 4);
    int*   eperm  = (int*)  alloc((size_t)NE * 4);
    int*   src_s  = (int*)  alloc((size_t)NE * 4);
    int*   dst_s  = (int*)  alloc((size_t)NE * 4);
    int*   hist   = (int*)  alloc((size_t)NN * 4);   // NN*4 is 256B-aligned size
    int*   ghist  = (int*)  alloc(256 * 4);          // contiguous with hist
    int*   rowptr = (int*)  alloc((size_t)(NN + 1) * 4);
    int*   cursor = (int*)  alloc((size_t)NN * 4);
    int*   grp    = (int*)  alloc((size_t)(NB + 1) * 4);
    size_t need = off;

    if (ws_size < need) return;  // fail validation rather than fault

    // ---- CSR build (dst-sorted edge order) + graph rowptr ----
    k_zero4<<<33, 256, 0, stream>>>((float4*)hist, ((long)NN * 4 + 256 * 4) / 16);
    k_hist<<<NE / 256, 256, 0, stream>>>(dst, hist);
    k_scan<<<1, 1024, 0, stream>>>(hist, rowptr, cursor);
    k_scatter<<<NE / 256, 256, 0, stream>>>(src, dst, cursor, eperm, src_s, dst_s);
    k_ghist<<<NN / 256, 256, 0, stream>>>(gid, ghist);
    k_gscan<<<1, 256, 0, stream>>>(ghist, grp);

    // ---- embeddings ----
    k_embed_h<<<(NN * 64) / 256, 256, 0, stream>>>(in_h, embhW, embhb, h, h16buf);
    k_embed_e_perm<<<(NE * 8) / 256, 256, 0, stream>>>(e_feat, eperm, embeW, embeb, e_s);

    k_zero4<<<4, 256, 0, stream>>>((float4*)stats, (NBANK * 256) / 4);  // zero banks once
    for (int l = 0; l < NL; ++l) {
        k_node_gemm<<<NG_BLOCKS, 256, 0, stream>>>(h16buf,
                                                   A_W + l * 4096, A_b + l * 64,
                                                   B_W + l * 4096, B_b + l * 64,
                                                   D_W + l * 4096, D_b + l * 64,
                                                   E_W + l * 4096, E_b + l * 64,
                                                   Ah, Bh, Dh, Eh);
        if (l == 0)
            k_edge_fwd<0><<<EF_BLOCKS, 256, 0, stream>>>(e_s, nullptr,
                C_W + l * 4096, C_b + l * 64, Dh, Eh, src_s, dst_s, ehat, stats);
        else if (l == 1)
            k_edge_fwd<1><<<EF_BLOCKS, 256, 0, stream>>>(e_s, e_s,
                C_W + l * 4096, C_b + l * 64, Dh, Eh, src_s, dst_s, ehat, stats);
        else
            k_edge_fwd<2><<<EF_BLOCKS, 256, 0, stream>>>(e_s, nullptr,
                C_W + l * 4096, C_b + l * 64, Dh, Eh, src_s, dst_s, ehat, stats);
        k_agg_node<<<AGG_BLOCKS, 256, 0, stream>>>(ehat, Bh, src_s, rowptr, Ah, hnew, stats);
        k_finstats2<<<1, 128, 0, stream>>>(stats, bneg + l * 64, bneb + l * 64,
                                           bnhg + l * 64, bnhb + l * 64);
        k_hbn_apply<<<NN / 16, 256, 0, stream>>>(h, h16buf, hnew, stats);
    }

    // ---- readout (atomic-free) ----
    k_graph_mean<<<NB / 4, 256, 0, stream>>>(h, grp, hg);

    // ---- fused MLP ----
    k_mlp<<<NB, 256, 0, stream>>>(hg, state, action, l1W, l1b, l2W, l2b, l3W, l3b,
                                  (float*)d_out);
}